// Round 4
// baseline (44490.112 us; speedup 1.0000x reference)
//
#include <hip/hip_runtime.h>
#include <hip/hip_fp16.h>

// ---------------------------------------------------------------------------
// AttentionEncoder: B=256, T=512, D=64, H=128
// Per-b independent 512-step attention-LSTM recurrence.
// Kernel 1 (pack): fuse biases; pack W1 (512x256) and [Wih|Whh] (512x192)
//                  rows into f16 pairs, laid out so each rnn thread's
//                  register-resident row loads coalesced.
// Kernel 2 (s2):   s2[b,d,s] = sum_t X[b,t,d]*W2[s,t] + b2[s]
// Kernel 3 (rnn):  1 block per b, 512 threads; ALL weights in VGPRs (f16,
//                  224 regs/thread), s2[b] staged in LDS (128 KB).
// ---------------------------------------------------------------------------

__device__ __forceinline__ float tanh_fast(float x) {
  // tanh(x) = 1 - 2/(exp(2x)+1); graceful at +-inf, no clamp needed.
  float e = __expf(2.f * x);
  return fmaf(-2.f, __builtin_amdgcn_rcpf(e + 1.f), 1.f);
}
__device__ __forceinline__ float sigm(float x) {
  return __builtin_amdgcn_rcpf(1.f + __expf(-x));
}
__device__ __forceinline__ unsigned pack2(float a, float b) {
  unsigned lo = __half_as_ushort(__float2half(a));
  unsigned hi = __half_as_ushort(__float2half(b));
  return lo | (hi << 16);
}
__device__ __forceinline__ float2 up2(unsigned u) {
  __half2 h = *reinterpret_cast<const __half2*>(&u);
  return __half22float2(h);
}

// ---- pack weights to f16 + fuse biases ------------------------------------
// W1P[k4*512 + t] (uint4) holds f16 W1[t][8k4 .. 8k4+7]   (k4 in [0,32))
// WZP[k4*512 + t] (uint4) holds f16 WZ[t][8k4 .. 8k4+7]   (k4 in [0,24))
//   where WZ[t][c] = c<64 ? Wih[t][c] : Whh[t][c-64]
__global__ __launch_bounds__(256) void pack_kernel(
    const float* __restrict__ W1, const float* __restrict__ Wih,
    const float* __restrict__ Whh, const float* __restrict__ bih,
    const float* __restrict__ bhh, uint4* __restrict__ W1P,
    uint4* __restrict__ WZP, float* __restrict__ bz) {
  int gid = blockIdx.x * 256 + threadIdx.x;
  if (gid < 512) bz[gid] = bih[gid] + bhh[gid];
  if (gid < 16384) {
    int k4 = gid >> 9, t = gid & 511;
    const float* src = W1 + t * 256 + k4 * 8;
    uint4 o;
    o.x = pack2(src[0], src[1]);
    o.y = pack2(src[2], src[3]);
    o.z = pack2(src[4], src[5]);
    o.w = pack2(src[6], src[7]);
    W1P[gid] = o;
  } else if (gid < 28672) {
    int g = gid - 16384;
    int k4 = g >> 9, t = g & 511;
    float v[8];
#pragma unroll
    for (int q = 0; q < 8; ++q) {
      int col = k4 * 8 + q;
      v[q] = (col < 64) ? Wih[t * 64 + col] : Whh[t * 128 + col - 64];
    }
    uint4 o;
    o.x = pack2(v[0], v[1]);
    o.y = pack2(v[2], v[3]);
    o.z = pack2(v[4], v[5]);
    o.w = pack2(v[6], v[7]);
    WZP[g] = o;
  }
}

// ---- s2 = einsum('btd,st->bds') + b2 --------------------------------------
__global__ __launch_bounds__(256) void s2_kernel(
    const float* __restrict__ X, const float* __restrict__ W2,
    const float* __restrict__ b2, float* __restrict__ s2) {
  __shared__ float Xs[64 * 68];
  __shared__ float W2sT[64 * 68];
  const int b = blockIdx.y;
  const int s0 = blockIdx.x * 64;
  const int tid = threadIdx.x;
  const int dq = tid & 15, sq = tid >> 4;
  float acc[4][4] = {{0.f, 0.f, 0.f, 0.f}};

  for (int t0 = 0; t0 < 512; t0 += 64) {
    __syncthreads();
    for (int i = tid; i < 4096; i += 256) {
      int tt = i >> 6, dd = i & 63;
      Xs[tt * 68 + dd] = X[((size_t)b * 512 + t0 + tt) * 64 + dd];
      int ss = i >> 6, t2 = i & 63;
      W2sT[t2 * 68 + ss] = W2[(size_t)(s0 + ss) * 512 + t0 + t2];
    }
    __syncthreads();
    const float4* Xs4 = (const float4*)Xs;
    const float4* W4 = (const float4*)W2sT;
#pragma unroll 8
    for (int tt = 0; tt < 64; ++tt) {
      float4 xv = Xs4[tt * 17 + dq];
      float4 wv = W4[tt * 17 + sq];
      float xa[4] = {xv.x, xv.y, xv.z, xv.w};
      float wa[4] = {wv.x, wv.y, wv.z, wv.w};
#pragma unroll
      for (int q = 0; q < 4; ++q)
#pragma unroll
        for (int r = 0; r < 4; ++r) acc[q][r] += xa[q] * wa[r];
    }
  }
  const float* bp = b2 + s0 + sq * 4;
  float b0 = bp[0], bx1 = bp[1], bx2 = bp[2], bx3 = bp[3];
#pragma unroll
  for (int q = 0; q < 4; ++q) {
    float4 o = make_float4(acc[q][0] + b0, acc[q][1] + bx1,
                           acc[q][2] + bx2, acc[q][3] + bx3);
    *(float4*)&s2[((size_t)b * 64 + dq * 4 + q) * 512 + s0 + sq * 4] = o;
  }
}

// ---- the recurrence -------------------------------------------------------
// grid 256 (one block per b), 512 threads (8 waves, 2/SIMD -> 256 VGPR cap).
__global__ __launch_bounds__(512, 2) void rnn_kernel(
    const float* __restrict__ X, const float* __restrict__ s2g,
    const uint4* __restrict__ W1P, const uint4* __restrict__ WZP,
    const float* __restrict__ b1, const float* __restrict__ bz,
    const float* __restrict__ W3, const float* __restrict__ b3p,
    float* __restrict__ out) {
  __shared__ float4 s2s4[64 * 128];  // 128 KB: s2[b], row d = 512 f32
  __shared__ float4 hc4[64];         // [h(128); c(128)]
  __shared__ float4 xh4[48];         // [x(64); h(128)]
  __shared__ float4 s1s4[128];       // s1 (512)
  __shared__ float4 w3s4[128];       // w3 (512)
  __shared__ float eb[64];
  __shared__ float zb[512];

  float* hc = (float*)hc4;
  float* xh = (float*)xh4;
  float* s1s = (float*)s1s4;
  float* w3s = (float*)w3s4;

  const int b = blockIdx.x;
  const int tid = threadIdx.x;
  const int lane = tid & 63;
  const int w = tid >> 6;

  // ---- one-time: weights into registers (coalesced uint4 loads) ----
  uint4 w1r[32];
#pragma unroll
  for (int k = 0; k < 32; ++k) w1r[k] = W1P[k * 512 + tid];
  uint4 wzr[24];
#pragma unroll
  for (int k = 0; k < 24; ++k) wzr[k] = WZP[k * 512 + tid];

  // ---- stage s2[b] into LDS ----
  {
    const float4* src = (const float4*)(s2g + (size_t)b * 32768);
    for (int i = tid; i < 8192; i += 512) s2s4[i] = src[i];
  }
  if (tid < 64) hc4[tid] = make_float4(0.f, 0.f, 0.f, 0.f);
  if (tid >= 64 && tid < 112) xh4[tid - 64] = make_float4(0.f, 0.f, 0.f, 0.f);
  w3s[tid] = W3[tid];
  const float b1r = b1[tid];
  const float bzr = bz[tid];
  const float b3v = b3p[0];
  // prefetch x_t for t=0 (wave 0 uses it in phase 3)
  float xpre = X[((size_t)b * 512 + 0) * 64 + lane];
  __syncthreads();

  for (int t = 0; t < 512; ++t) {
    // phase 1: s1[tid] = [h;c] . W1[tid,:] + b1   (weights in regs)
    float acc = b1r;
#pragma unroll
    for (int k = 0; k < 32; ++k) {
      float4 ha = hc4[2 * k], hb = hc4[2 * k + 1];
      uint4 ww = w1r[k];
      float2 p;
      p = up2(ww.x); acc = fmaf(ha.x, p.x, acc); acc = fmaf(ha.y, p.y, acc);
      p = up2(ww.y); acc = fmaf(ha.z, p.x, acc); acc = fmaf(ha.w, p.y, acc);
      p = up2(ww.z); acc = fmaf(hb.x, p.x, acc); acc = fmaf(hb.y, p.y, acc);
      p = up2(ww.w); acc = fmaf(hb.z, p.x, acc); acc = fmaf(hb.w, p.y, acc);
    }
    s1s[tid] = acc;
    __syncthreads();

    // phase 2: e[d] = sum_t tanh(s1[t] + s2[d,t]) * w3[t] + b3
    {
      float loc[8] = {0.f, 0.f, 0.f, 0.f, 0.f, 0.f, 0.f, 0.f};
#pragma unroll
      for (int i = 0; i < 2; ++i) {
        int f4 = lane + 64 * i;
        float4 sv = s1s4[f4];
        float4 wv = w3s4[f4];
#pragma unroll
        for (int dd = 0; dd < 8; ++dd) {
          int d = w + 8 * dd;
          float4 s2v = s2s4[d * 128 + f4];
          loc[dd] += tanh_fast(sv.x + s2v.x) * wv.x;
          loc[dd] += tanh_fast(sv.y + s2v.y) * wv.y;
          loc[dd] += tanh_fast(sv.z + s2v.z) * wv.z;
          loc[dd] += tanh_fast(sv.w + s2v.w) * wv.w;
        }
      }
#pragma unroll
      for (int dd = 0; dd < 8; ++dd) {
        float local = loc[dd];
#pragma unroll
        for (int off = 32; off; off >>= 1) local += __shfl_xor(local, off);
        if (lane == 0) eb[w + 8 * dd] = local + b3v;
      }
    }
    __syncthreads();

    // phase 3: softmax over d (64) + x = a * x_t  (wave 0 only)
    if (w == 0) {
      float e = eb[lane];
      float m = e;
#pragma unroll
      for (int off = 32; off; off >>= 1) m = fmaxf(m, __shfl_xor(m, off));
      float p = __expf(e - m);
      float s = p;
#pragma unroll
      for (int off = 32; off; off >>= 1) s += __shfl_xor(s, off);
      xh[lane] = __builtin_amdgcn_rcpf(s) * p * xpre;
      // prefetch next step's x row (full step of latency hiding)
      int tn = (t + 1 < 512) ? t + 1 : 511;
      xpre = X[((size_t)b * 512 + tn) * 64 + lane];
    }
    __syncthreads();

    // phase 4: z[tid] = [x;h] . WZ[tid,:] + bih + bhh   (weights in regs)
    float zacc = bzr;
#pragma unroll
    for (int k = 0; k < 24; ++k) {
      float4 xa = xh4[2 * k], xb_ = xh4[2 * k + 1];
      uint4 ww = wzr[k];
      float2 p;
      p = up2(ww.x); zacc = fmaf(xa.x, p.x, zacc); zacc = fmaf(xa.y, p.y, zacc);
      p = up2(ww.y); zacc = fmaf(xa.z, p.x, zacc); zacc = fmaf(xa.w, p.y, zacc);
      p = up2(ww.z); zacc = fmaf(xb_.x, p.x, zacc); zacc = fmaf(xb_.y, p.y, zacc);
      p = up2(ww.w); zacc = fmaf(xb_.z, p.x, zacc); zacc = fmaf(xb_.w, p.y, zacc);
    }
    zb[tid] = zacc;
    __syncthreads();

    // phase 5: LSTM gates, write h
    if (tid < 128) {
      float iv = zb[tid], fv = zb[tid + 128], gv = zb[tid + 256], ov = zb[tid + 384];
      float c = hc[128 + tid];
      float cn = sigm(fv) * c + sigm(iv) * tanh_fast(gv);
      float hn = sigm(ov) * tanh_fast(cn);
      hc[tid] = hn;
      hc[128 + tid] = cn;
      xh[64 + tid] = hn;
      out[((size_t)b * 512 + t) * 128 + tid] = hn;
    }
    __syncthreads();
  }
}

extern "C" void kernel_launch(void* const* d_in, const int* in_sizes, int n_in,
                              void* d_out, int out_size, void* d_ws, size_t ws_size,
                              hipStream_t stream) {
  const float* X   = (const float*)d_in[0];
  const float* Wih = (const float*)d_in[1];
  const float* Whh = (const float*)d_in[2];
  const float* bih = (const float*)d_in[3];
  const float* bhh = (const float*)d_in[4];
  const float* W1  = (const float*)d_in[5];
  const float* b1  = (const float*)d_in[6];
  const float* W2  = (const float*)d_in[7];
  const float* b2  = (const float*)d_in[8];
  const float* W3  = (const float*)d_in[9];
  const float* b3  = (const float*)d_in[10];
  float* out = (float*)d_out;
  float* ws = (float*)d_ws;

  float* s2  = ws;                          // 8,388,608 f32 (32 MB)
  uint4* W1P = (uint4*)(ws + 8388608);      // 16384 uint4 (256 KB)
  uint4* WZP = (uint4*)(ws + 8388608 + 65536);  // 12288 uint4 (192 KB)
  float* bz  = ws + 8388608 + 65536 + 49152;    // 512 f32
  // total ~34.0 MB of ws

  hipLaunchKernelGGL(pack_kernel, dim3(112), dim3(256), 0, stream,
                     W1, Wih, Whh, bih, bhh, W1P, WZP, bz);
  hipLaunchKernelGGL(s2_kernel, dim3(8, 256), dim3(256), 0, stream,
                     X, W2, b2, s2);
  hipLaunchKernelGGL(rnn_kernel, dim3(256), dim3(512), 0, stream,
                     X, s2, W1P, WZP, b1, bz, W3, b3, out);
}

// Round 6
// 24375.903 us; speedup vs baseline: 1.8252x; 1.8252x over previous
//
#include <hip/hip_runtime.h>
#include <hip/hip_fp16.h>

// ---------------------------------------------------------------------------
// AttentionEncoder: B=256, T=512, D=64, H=128
// Kernel 3 (rnn): 1 block per b, 512 threads; weights held in 56 NAMED uint4
// VGPR variables (f16 pairs, 224 VGPRs) -- named scalars, not arrays, so the
// compiler cannot leave them in scratch allocas (round-4 failure: VGPR=128,
// 37 GB scratch reads, 44 ms).
// ---------------------------------------------------------------------------

__device__ __forceinline__ float tanh_fast(float x) {
  float e = __expf(2.f * x);
  return fmaf(-2.f, __builtin_amdgcn_rcpf(e + 1.f), 1.f);
}
__device__ __forceinline__ float sigm(float x) {
  return __builtin_amdgcn_rcpf(1.f + __expf(-x));
}
__device__ __forceinline__ unsigned pack2(float a, float b) {
  unsigned lo = __half_as_ushort(__float2half(a));
  unsigned hi = __half_as_ushort(__float2half(b));
  return lo | (hi << 16);
}
// by-value f16 unpack (no address-taking -> no alloca hazard); the
// fmaf(f16->f32, f32, f32) pattern maps to v_fma_mix_f32.
__device__ __forceinline__ float h2lo(unsigned u) {
  return __half2float(__ushort_as_half((unsigned short)(u & 0xffffu)));
}
__device__ __forceinline__ float h2hi(unsigned u) {
  return __half2float(__ushort_as_half((unsigned short)(u >> 16)));
}

// ---- pack weights to f16 + fuse biases ------------------------------------
// W1P[k4*512 + t] (uint4) holds f16 W1[t][8k4 .. 8k4+7]   (k4 in [0,32))
// WZP[k4*512 + t] (uint4) holds f16 WZ[t][8k4 .. 8k4+7]   (k4 in [0,24))
//   where WZ[t][c] = c<64 ? Wih[t][c] : Whh[t][c-64]
__global__ __launch_bounds__(256) void pack_kernel(
    const float* __restrict__ W1, const float* __restrict__ Wih,
    const float* __restrict__ Whh, const float* __restrict__ bih,
    const float* __restrict__ bhh, uint4* __restrict__ W1P,
    uint4* __restrict__ WZP, float* __restrict__ bz) {
  int gid = blockIdx.x * 256 + threadIdx.x;
  if (gid < 512) bz[gid] = bih[gid] + bhh[gid];
  if (gid < 16384) {
    int k4 = gid >> 9, t = gid & 511;
    const float* src = W1 + t * 256 + k4 * 8;
    uint4 o;
    o.x = pack2(src[0], src[1]);
    o.y = pack2(src[2], src[3]);
    o.z = pack2(src[4], src[5]);
    o.w = pack2(src[6], src[7]);
    W1P[gid] = o;
  } else if (gid < 28672) {
    int g = gid - 16384;
    int k4 = g >> 9, t = g & 511;
    float v[8];
#pragma unroll
    for (int q = 0; q < 8; ++q) {
      int col = k4 * 8 + q;
      v[q] = (col < 64) ? Wih[t * 64 + col] : Whh[t * 128 + col - 64];
    }
    uint4 o;
    o.x = pack2(v[0], v[1]);
    o.y = pack2(v[2], v[3]);
    o.z = pack2(v[4], v[5]);
    o.w = pack2(v[6], v[7]);
    WZP[g] = o;
  }
}

// ---- s2 = einsum('btd,st->bds') + b2 --------------------------------------
__global__ __launch_bounds__(256) void s2_kernel(
    const float* __restrict__ X, const float* __restrict__ W2,
    const float* __restrict__ b2, float* __restrict__ s2) {
  __shared__ float Xs[64 * 68];
  __shared__ float W2sT[64 * 68];
  const int b = blockIdx.y;
  const int s0 = blockIdx.x * 64;
  const int tid = threadIdx.x;
  const int dq = tid & 15, sq = tid >> 4;
  float acc[4][4] = {{0.f, 0.f, 0.f, 0.f}};

  for (int t0 = 0; t0 < 512; t0 += 64) {
    __syncthreads();
    for (int i = tid; i < 4096; i += 256) {
      int tt = i >> 6, dd = i & 63;
      Xs[tt * 68 + dd] = X[((size_t)b * 512 + t0 + tt) * 64 + dd];
      int ss = i >> 6, t2 = i & 63;
      W2sT[t2 * 68 + ss] = W2[(size_t)(s0 + ss) * 512 + t0 + t2];
    }
    __syncthreads();
    const float4* Xs4 = (const float4*)Xs;
    const float4* W4 = (const float4*)W2sT;
#pragma unroll 8
    for (int tt = 0; tt < 64; ++tt) {
      float4 xv = Xs4[tt * 17 + dq];
      float4 wv = W4[tt * 17 + sq];
      float xa[4] = {xv.x, xv.y, xv.z, xv.w};
      float wa[4] = {wv.x, wv.y, wv.z, wv.w};
#pragma unroll
      for (int q = 0; q < 4; ++q)
#pragma unroll
        for (int r = 0; r < 4; ++r) acc[q][r] += xa[q] * wa[r];
    }
  }
  const float* bp = b2 + s0 + sq * 4;
  float b0 = bp[0], bx1 = bp[1], bx2 = bp[2], bx3 = bp[3];
#pragma unroll
  for (int q = 0; q < 4; ++q) {
    float4 o = make_float4(acc[q][0] + b0, acc[q][1] + bx1,
                           acc[q][2] + bx2, acc[q][3] + bx3);
    *(float4*)&s2[((size_t)b * 64 + dq * 4 + q) * 512 + s0 + sq * 4] = o;
  }
}

// ---- the recurrence -------------------------------------------------------
// grid 256 (one block per b), 512 threads (8 waves, 2/SIMD -> 256 VGPR cap).
__global__ __launch_bounds__(512, 2) void rnn_kernel(
    const float* __restrict__ X, const float* __restrict__ s2g,
    const uint4* __restrict__ W1P, const uint4* __restrict__ WZP,
    const float* __restrict__ b1, const float* __restrict__ bz,
    const float* __restrict__ W3, const float* __restrict__ b3p,
    float* __restrict__ out) {
  __shared__ float4 s2s4[64 * 128];  // 128 KB: s2[b], row d = 512 f32
  __shared__ float4 hc4[64];         // [h(128); c(128)]
  __shared__ float4 xh4[48];         // [x(64); h(128)]
  __shared__ float4 s1s4[128];       // s1 (512)
  __shared__ float4 w3s4[128];       // w3 (512)
  __shared__ float eb[64];
  __shared__ float zb[512];

  float* hc = (float*)hc4;
  float* xh = (float*)xh4;
  float* s1s = (float*)s1s4;
  float* w3s = (float*)w3s4;

  const int b = blockIdx.x;
  const int tid = threadIdx.x;
  const int lane = tid & 63;
  const int w = tid >> 6;

  // ---- one-time: weights into NAMED register variables (coalesced) ----
#define LD_W1(K) const uint4 w1_##K = W1P[(K) * 512 + tid];
  LD_W1(0) LD_W1(1) LD_W1(2) LD_W1(3) LD_W1(4) LD_W1(5) LD_W1(6) LD_W1(7)
  LD_W1(8) LD_W1(9) LD_W1(10) LD_W1(11) LD_W1(12) LD_W1(13) LD_W1(14) LD_W1(15)
  LD_W1(16) LD_W1(17) LD_W1(18) LD_W1(19) LD_W1(20) LD_W1(21) LD_W1(22) LD_W1(23)
  LD_W1(24) LD_W1(25) LD_W1(26) LD_W1(27) LD_W1(28) LD_W1(29) LD_W1(30) LD_W1(31)
#define LD_WZ(K) const uint4 wz_##K = WZP[(K) * 512 + tid];
  LD_WZ(0) LD_WZ(1) LD_WZ(2) LD_WZ(3) LD_WZ(4) LD_WZ(5) LD_WZ(6) LD_WZ(7)
  LD_WZ(8) LD_WZ(9) LD_WZ(10) LD_WZ(11) LD_WZ(12) LD_WZ(13) LD_WZ(14) LD_WZ(15)
  LD_WZ(16) LD_WZ(17) LD_WZ(18) LD_WZ(19) LD_WZ(20) LD_WZ(21) LD_WZ(22) LD_WZ(23)

  // ---- stage s2[b] into LDS ----
  {
    const float4* src = (const float4*)(s2g + (size_t)b * 32768);
    for (int i = tid; i < 8192; i += 512) s2s4[i] = src[i];
  }
  if (tid < 64) hc4[tid] = make_float4(0.f, 0.f, 0.f, 0.f);
  if (tid >= 64 && tid < 112) xh4[tid - 64] = make_float4(0.f, 0.f, 0.f, 0.f);
  w3s[tid] = W3[tid];
  const float b1r = b1[tid];
  const float bzr = bz[tid];
  const float b3v = b3p[0];
  float xpre = X[((size_t)b * 512 + 0) * 64 + lane];
  __syncthreads();

  for (int t = 0; t < 512; ++t) {
    // phase 1: s1[tid] = [h;c] . W1[tid,:] + b1   (weights in regs)
    float a0 = b1r, a1 = 0.f, a2 = 0.f, a3 = 0.f;
#define P1(K, A) {                                   \
    const float4 ha = hc4[2 * (K)];                  \
    const float4 hb = hc4[2 * (K) + 1];              \
    A = fmaf(h2lo(w1_##K.x), ha.x, A);               \
    A = fmaf(h2hi(w1_##K.x), ha.y, A);               \
    A = fmaf(h2lo(w1_##K.y), ha.z, A);               \
    A = fmaf(h2hi(w1_##K.y), ha.w, A);               \
    A = fmaf(h2lo(w1_##K.z), hb.x, A);               \
    A = fmaf(h2hi(w1_##K.z), hb.y, A);               \
    A = fmaf(h2lo(w1_##K.w), hb.z, A);               \
    A = fmaf(h2hi(w1_##K.w), hb.w, A);               \
  }
    P1(0, a0) P1(1, a1) P1(2, a2) P1(3, a3)
    P1(4, a0) P1(5, a1) P1(6, a2) P1(7, a3)
    P1(8, a0) P1(9, a1) P1(10, a2) P1(11, a3)
    P1(12, a0) P1(13, a1) P1(14, a2) P1(15, a3)
    P1(16, a0) P1(17, a1) P1(18, a2) P1(19, a3)
    P1(20, a0) P1(21, a1) P1(22, a2) P1(23, a3)
    P1(24, a0) P1(25, a1) P1(26, a2) P1(27, a3)
    P1(28, a0) P1(29, a1) P1(30, a2) P1(31, a3)
    s1s[tid] = (a0 + a1) + (a2 + a3);
    __syncthreads();

    // phase 2: e[d] = sum_t tanh(s1[t] + s2[d,t]) * w3[t] + b3
    {
      float loc[8] = {0.f, 0.f, 0.f, 0.f, 0.f, 0.f, 0.f, 0.f};
#pragma unroll
      for (int i = 0; i < 2; ++i) {
        int f4 = lane + 64 * i;
        float4 sv = s1s4[f4];
        float4 wv = w3s4[f4];
#pragma unroll
        for (int dd = 0; dd < 8; ++dd) {
          int d = w + 8 * dd;
          float4 s2v = s2s4[d * 128 + f4];
          loc[dd] += tanh_fast(sv.x + s2v.x) * wv.x;
          loc[dd] += tanh_fast(sv.y + s2v.y) * wv.y;
          loc[dd] += tanh_fast(sv.z + s2v.z) * wv.z;
          loc[dd] += tanh_fast(sv.w + s2v.w) * wv.w;
        }
      }
#pragma unroll
      for (int dd = 0; dd < 8; ++dd) {
        float local = loc[dd];
#pragma unroll
        for (int off = 32; off; off >>= 1) local += __shfl_xor(local, off);
        if (lane == 0) eb[w + 8 * dd] = local + b3v;
      }
    }
    __syncthreads();

    // phase 3: softmax over d (64) + x = a * x_t  (wave 0 only)
    if (w == 0) {
      float e = eb[lane];
      float m = e;
#pragma unroll
      for (int off = 32; off; off >>= 1) m = fmaxf(m, __shfl_xor(m, off));
      float p = __expf(e - m);
      float s = p;
#pragma unroll
      for (int off = 32; off; off >>= 1) s += __shfl_xor(s, off);
      xh[lane] = __builtin_amdgcn_rcpf(s) * p * xpre;
      int tn = (t + 1 < 512) ? t + 1 : 511;
      xpre = X[((size_t)b * 512 + tn) * 64 + lane];
    }
    __syncthreads();

    // phase 4: z[tid] = [x;h] . WZ[tid,:] + bih + bhh   (weights in regs)
    float z0 = bzr, z1 = 0.f, z2 = 0.f, z3 = 0.f;
#define P4(K, A) {                                   \
    const float4 xa = xh4[2 * (K)];                  \
    const float4 xb = xh4[2 * (K) + 1];              \
    A = fmaf(h2lo(wz_##K.x), xa.x, A);               \
    A = fmaf(h2hi(wz_##K.x), xa.y, A);               \
    A = fmaf(h2lo(wz_##K.y), xa.z, A);               \
    A = fmaf(h2hi(wz_##K.y), xa.w, A);               \
    A = fmaf(h2lo(wz_##K.z), xb.x, A);               \
    A = fmaf(h2hi(wz_##K.z), xb.y, A);               \
    A = fmaf(h2lo(wz_##K.w), xb.z, A);               \
    A = fmaf(h2hi(wz_##K.w), xb.w, A);               \
  }
    P4(0, z0) P4(1, z1) P4(2, z2) P4(3, z3)
    P4(4, z0) P4(5, z1) P4(6, z2) P4(7, z3)
    P4(8, z0) P4(9, z1) P4(10, z2) P4(11, z3)
    P4(12, z0) P4(13, z1) P4(14, z2) P4(15, z3)
    P4(16, z0) P4(17, z1) P4(18, z2) P4(19, z3)
    P4(20, z0) P4(21, z1) P4(22, z2) P4(23, z3)
    zb[tid] = (z0 + z1) + (z2 + z3);
    __syncthreads();

    // phase 5: LSTM gates, write h
    if (tid < 128) {
      float iv = zb[tid], fv = zb[tid + 128], gv = zb[tid + 256], ov = zb[tid + 384];
      float c = hc[128 + tid];
      float cn = sigm(fv) * c + sigm(iv) * tanh_fast(gv);
      float hn = sigm(ov) * tanh_fast(cn);
      hc[tid] = hn;
      hc[128 + tid] = cn;
      xh[64 + tid] = hn;
      out[((size_t)b * 512 + t) * 128 + tid] = hn;
    }
    __syncthreads();
  }
}

extern "C" void kernel_launch(void* const* d_in, const int* in_sizes, int n_in,
                              void* d_out, int out_size, void* d_ws, size_t ws_size,
                              hipStream_t stream) {
  const float* X   = (const float*)d_in[0];
  const float* Wih = (const float*)d_in[1];
  const float* Whh = (const float*)d_in[2];
  const float* bih = (const float*)d_in[3];
  const float* bhh = (const float*)d_in[4];
  const float* W1  = (const float*)d_in[5];
  const float* b1  = (const float*)d_in[6];
  const float* W2  = (const float*)d_in[7];
  const float* b2  = (const float*)d_in[8];
  const float* W3  = (const float*)d_in[9];
  const float* b3  = (const float*)d_in[10];
  float* out = (float*)d_out;
  float* ws = (float*)d_ws;

  float* s2  = ws;                          // 8,388,608 f32 (32 MB)
  uint4* W1P = (uint4*)(ws + 8388608);      // 16384 uint4 (256 KB)
  uint4* WZP = (uint4*)(ws + 8388608 + 65536);  // 12288 uint4 (192 KB)
  float* bz  = ws + 8388608 + 65536 + 49152;    // 512 f32

  hipLaunchKernelGGL(pack_kernel, dim3(112), dim3(256), 0, stream,
                     W1, Wih, Whh, bih, bhh, W1P, WZP, bz);
  hipLaunchKernelGGL(s2_kernel, dim3(8, 256), dim3(256), 0, stream,
                     X, W2, b2, s2);
  hipLaunchKernelGGL(rnn_kernel, dim3(256), dim3(512), 0, stream,
                     X, s2, W1P, WZP, b1, bz, W3, b3, out);
}

// Round 7
// 24327.985 us; speedup vs baseline: 1.8288x; 1.0020x over previous
//
#include <hip/hip_runtime.h>
#include <hip/hip_fp16.h>

// ---------------------------------------------------------------------------
// AttentionEncoder: B=256, T=512, D=64, H=128
// rnn kernel: 1 block per b, 512 threads, EXACTLY 2 waves/EU pinned via
// amdgpu_waves_per_eu(2,2) -> 256-VGPR cap, so the 224 f16-pair weight
// registers (56 named uint4) actually fit. Rounds 4/6 failed because
// __launch_bounds__(512,2) was applied as CUDA min-2-blocks -> 128-VGPR cap
// -> all weights spilled to scratch (37 GB HBM reads, 24-44 ms).
// ---------------------------------------------------------------------------

__device__ __forceinline__ float tanh_fast(float x) {
  float e = __expf(2.f * x);
  return fmaf(-2.f, __builtin_amdgcn_rcpf(e + 1.f), 1.f);
}
__device__ __forceinline__ float sigm(float x) {
  return __builtin_amdgcn_rcpf(1.f + __expf(-x));
}
__device__ __forceinline__ unsigned pack2(float a, float b) {
  unsigned lo = __half_as_ushort(__float2half(a));
  unsigned hi = __half_as_ushort(__float2half(b));
  return lo | (hi << 16);
}
// by-value f16 unpack; fmaf(f16->f32, f32, f32) maps to v_fma_mix_f32.
__device__ __forceinline__ float h2lo(unsigned u) {
  return __half2float(__ushort_as_half((unsigned short)(u & 0xffffu)));
}
__device__ __forceinline__ float h2hi(unsigned u) {
  return __half2float(__ushort_as_half((unsigned short)(u >> 16)));
}

// ---- pack weights to f16 + fuse biases ------------------------------------
// W1P[k4*512 + t] (uint4) holds f16 W1[t][8k4 .. 8k4+7]   (k4 in [0,32))
// WZP[k4*512 + t] (uint4) holds f16 WZ[t][8k4 .. 8k4+7]   (k4 in [0,24))
//   where WZ[t][c] = c<64 ? Wih[t][c] : Whh[t][c-64]
__global__ __launch_bounds__(256) void pack_kernel(
    const float* __restrict__ W1, const float* __restrict__ Wih,
    const float* __restrict__ Whh, const float* __restrict__ bih,
    const float* __restrict__ bhh, uint4* __restrict__ W1P,
    uint4* __restrict__ WZP, float* __restrict__ bz) {
  int gid = blockIdx.x * 256 + threadIdx.x;
  if (gid < 512) bz[gid] = bih[gid] + bhh[gid];
  if (gid < 16384) {
    int k4 = gid >> 9, t = gid & 511;
    const float* src = W1 + t * 256 + k4 * 8;
    uint4 o;
    o.x = pack2(src[0], src[1]);
    o.y = pack2(src[2], src[3]);
    o.z = pack2(src[4], src[5]);
    o.w = pack2(src[6], src[7]);
    W1P[gid] = o;
  } else if (gid < 28672) {
    int g = gid - 16384;
    int k4 = g >> 9, t = g & 511;
    float v[8];
#pragma unroll
    for (int q = 0; q < 8; ++q) {
      int col = k4 * 8 + q;
      v[q] = (col < 64) ? Wih[t * 64 + col] : Whh[t * 128 + col - 64];
    }
    uint4 o;
    o.x = pack2(v[0], v[1]);
    o.y = pack2(v[2], v[3]);
    o.z = pack2(v[4], v[5]);
    o.w = pack2(v[6], v[7]);
    WZP[g] = o;
  }
}

// ---- s2 = einsum('btd,st->bds') + b2 --------------------------------------
__global__ __launch_bounds__(256) void s2_kernel(
    const float* __restrict__ X, const float* __restrict__ W2,
    const float* __restrict__ b2, float* __restrict__ s2) {
  __shared__ float Xs[64 * 68];
  __shared__ float W2sT[64 * 68];
  const int b = blockIdx.y;
  const int s0 = blockIdx.x * 64;
  const int tid = threadIdx.x;
  const int dq = tid & 15, sq = tid >> 4;
  float acc[4][4] = {{0.f, 0.f, 0.f, 0.f}};

  for (int t0 = 0; t0 < 512; t0 += 64) {
    __syncthreads();
    for (int i = tid; i < 4096; i += 256) {
      int tt = i >> 6, dd = i & 63;
      Xs[tt * 68 + dd] = X[((size_t)b * 512 + t0 + tt) * 64 + dd];
      int ss = i >> 6, t2 = i & 63;
      W2sT[t2 * 68 + ss] = W2[(size_t)(s0 + ss) * 512 + t0 + t2];
    }
    __syncthreads();
    const float4* Xs4 = (const float4*)Xs;
    const float4* W4 = (const float4*)W2sT;
#pragma unroll 8
    for (int tt = 0; tt < 64; ++tt) {
      float4 xv = Xs4[tt * 17 + dq];
      float4 wv = W4[tt * 17 + sq];
      float xa[4] = {xv.x, xv.y, xv.z, xv.w};
      float wa[4] = {wv.x, wv.y, wv.z, wv.w};
#pragma unroll
      for (int q = 0; q < 4; ++q)
#pragma unroll
        for (int r = 0; r < 4; ++r) acc[q][r] += xa[q] * wa[r];
    }
  }
  const float* bp = b2 + s0 + sq * 4;
  float b0 = bp[0], bx1 = bp[1], bx2 = bp[2], bx3 = bp[3];
#pragma unroll
  for (int q = 0; q < 4; ++q) {
    float4 o = make_float4(acc[q][0] + b0, acc[q][1] + bx1,
                           acc[q][2] + bx2, acc[q][3] + bx3);
    *(float4*)&s2[((size_t)b * 64 + dq * 4 + q) * 512 + s0 + sq * 4] = o;
  }
}

// ---- the recurrence -------------------------------------------------------
// grid 256 (one block per b), 512 threads; EXACTLY 2 waves/EU (256-VGPR cap).
__global__
__attribute__((amdgpu_flat_work_group_size(512, 512), amdgpu_waves_per_eu(2, 2)))
void rnn_kernel(
    const float* __restrict__ X, const float* __restrict__ s2g,
    const uint4* __restrict__ W1P, const uint4* __restrict__ WZP,
    const float* __restrict__ b1, const float* __restrict__ bz,
    const float* __restrict__ W3, const float* __restrict__ b3p,
    float* __restrict__ out) {
  __shared__ float4 s2s4[64 * 128];  // 128 KB: s2[b], row d = 512 f32
  __shared__ float4 hc4[64];         // [h(128); c(128)]
  __shared__ float4 xh4[48];         // [x(64); h(128)]
  __shared__ float4 s1s4[128];       // s1 (512)
  __shared__ float4 w3s4[128];       // w3 (512)
  __shared__ float eb[64];
  __shared__ float zb[512];

  float* hc = (float*)hc4;
  float* xh = (float*)xh4;
  float* s1s = (float*)s1s4;
  float* w3s = (float*)w3s4;

  const int b = blockIdx.x;
  const int tid = threadIdx.x;
  const int lane = tid & 63;
  const int w = tid >> 6;

  // ---- stage s2[b] into LDS first (low register pressure here) ----
  {
    const float4* src = (const float4*)(s2g + (size_t)b * 32768);
    for (int i = tid; i < 8192; i += 512) s2s4[i] = src[i];
  }
  if (tid < 64) hc4[tid] = make_float4(0.f, 0.f, 0.f, 0.f);
  if (tid >= 64 && tid < 112) xh4[tid - 64] = make_float4(0.f, 0.f, 0.f, 0.f);
  w3s[tid] = W3[tid];
  const float b1r = b1[tid];
  const float bzr = bz[tid];
  const float b3v = b3p[0];
  float xpre = X[((size_t)b * 512 + 0) * 64 + lane];

  // ---- one-time: weights into NAMED register variables (coalesced) ----
#define LD_W1(K) const uint4 w1_##K = W1P[(K) * 512 + tid];
  LD_W1(0) LD_W1(1) LD_W1(2) LD_W1(3) LD_W1(4) LD_W1(5) LD_W1(6) LD_W1(7)
  LD_W1(8) LD_W1(9) LD_W1(10) LD_W1(11) LD_W1(12) LD_W1(13) LD_W1(14) LD_W1(15)
  LD_W1(16) LD_W1(17) LD_W1(18) LD_W1(19) LD_W1(20) LD_W1(21) LD_W1(22) LD_W1(23)
  LD_W1(24) LD_W1(25) LD_W1(26) LD_W1(27) LD_W1(28) LD_W1(29) LD_W1(30) LD_W1(31)
#define LD_WZ(K) const uint4 wz_##K = WZP[(K) * 512 + tid];
  LD_WZ(0) LD_WZ(1) LD_WZ(2) LD_WZ(3) LD_WZ(4) LD_WZ(5) LD_WZ(6) LD_WZ(7)
  LD_WZ(8) LD_WZ(9) LD_WZ(10) LD_WZ(11) LD_WZ(12) LD_WZ(13) LD_WZ(14) LD_WZ(15)
  LD_WZ(16) LD_WZ(17) LD_WZ(18) LD_WZ(19) LD_WZ(20) LD_WZ(21) LD_WZ(22) LD_WZ(23)

  __syncthreads();

  for (int t = 0; t < 512; ++t) {
    // phase 1: s1[tid] = [h;c] . W1[tid,:] + b1   (weights in regs)
    float a0 = b1r, a1 = 0.f, a2 = 0.f, a3 = 0.f;
#define P1(K, A) {                                   \
    const float4 ha = hc4[2 * (K)];                  \
    const float4 hb = hc4[2 * (K) + 1];              \
    A = fmaf(h2lo(w1_##K.x), ha.x, A);               \
    A = fmaf(h2hi(w1_##K.x), ha.y, A);               \
    A = fmaf(h2lo(w1_##K.y), ha.z, A);               \
    A = fmaf(h2hi(w1_##K.y), ha.w, A);               \
    A = fmaf(h2lo(w1_##K.z), hb.x, A);               \
    A = fmaf(h2hi(w1_##K.z), hb.y, A);               \
    A = fmaf(h2lo(w1_##K.w), hb.z, A);               \
    A = fmaf(h2hi(w1_##K.w), hb.w, A);               \
  }
    P1(0, a0) P1(1, a1) P1(2, a2) P1(3, a3)
    P1(4, a0) P1(5, a1) P1(6, a2) P1(7, a3)
    P1(8, a0) P1(9, a1) P1(10, a2) P1(11, a3)
    P1(12, a0) P1(13, a1) P1(14, a2) P1(15, a3)
    P1(16, a0) P1(17, a1) P1(18, a2) P1(19, a3)
    P1(20, a0) P1(21, a1) P1(22, a2) P1(23, a3)
    P1(24, a0) P1(25, a1) P1(26, a2) P1(27, a3)
    P1(28, a0) P1(29, a1) P1(30, a2) P1(31, a3)
    s1s[tid] = (a0 + a1) + (a2 + a3);
    __syncthreads();

    // phase 2: e[d] = sum_t tanh(s1[t] + s2[d,t]) * w3[t] + b3
    {
      float l0 = 0.f, l1 = 0.f, l2 = 0.f, l3 = 0.f;
      float l4 = 0.f, l5 = 0.f, l6 = 0.f, l7 = 0.f;
#define P2I(I) {                                                        \
      const int f4 = lane + 64 * (I);                                   \
      const float4 sv = s1s4[f4];                                       \
      const float4 wv = w3s4[f4];                                       \
      float tx, ty, tz, tw;                                             \
      const float4* rowp = &s2s4[w * 128 + f4];                         \
      /* d = w + 8*dd -> row stride 8*128 float4 */                     \
0;                                                                      \
    }
#undef P2I
#define P2D(DD, L) {                                                    \
      const float4 s2v = rowp[(DD) * 8 * 128];                          \
      L += tanh_fast(sv.x + s2v.x) * wv.x;                              \
      L += tanh_fast(sv.y + s2v.y) * wv.y;                              \
      L += tanh_fast(sv.z + s2v.z) * wv.z;                              \
      L += tanh_fast(sv.w + s2v.w) * wv.w;                              \
    }
#pragma unroll
      for (int i = 0; i < 2; ++i) {
        const int f4 = lane + 64 * i;
        const float4 sv = s1s4[f4];
        const float4 wv = w3s4[f4];
        const float4* rowp = &s2s4[w * 128 + f4];
        P2D(0, l0) P2D(1, l1) P2D(2, l2) P2D(3, l3)
        P2D(4, l4) P2D(5, l5) P2D(6, l6) P2D(7, l7)
      }
#define P2R(DD, L) {                                                    \
      float local = L;                                                  \
      _Pragma("unroll")                                                 \
      for (int off = 32; off; off >>= 1) local += __shfl_xor(local, off);\
      if (lane == 0) eb[w + 8 * (DD)] = local + b3v;                    \
    }
      P2R(0, l0) P2R(1, l1) P2R(2, l2) P2R(3, l3)
      P2R(4, l4) P2R(5, l5) P2R(6, l6) P2R(7, l7)
    }
    __syncthreads();

    // phase 3: softmax over d (64) + x = a * x_t  (wave 0 only)
    if (w == 0) {
      float e = eb[lane];
      float m = e;
#pragma unroll
      for (int off = 32; off; off >>= 1) m = fmaxf(m, __shfl_xor(m, off));
      float p = __expf(e - m);
      float s = p;
#pragma unroll
      for (int off = 32; off; off >>= 1) s += __shfl_xor(s, off);
      xh[lane] = __builtin_amdgcn_rcpf(s) * p * xpre;
      int tn = (t + 1 < 512) ? t + 1 : 511;
      xpre = X[((size_t)b * 512 + tn) * 64 + lane];
    }
    __syncthreads();

    // phase 4: z[tid] = [x;h] . WZ[tid,:] + bih + bhh   (weights in regs)
    float z0 = bzr, z1 = 0.f, z2 = 0.f, z3 = 0.f;
#define P4(K, A) {                                   \
    const float4 xa = xh4[2 * (K)];                  \
    const float4 xb = xh4[2 * (K) + 1];              \
    A = fmaf(h2lo(wz_##K.x), xa.x, A);               \
    A = fmaf(h2hi(wz_##K.x), xa.y, A);               \
    A = fmaf(h2lo(wz_##K.y), xa.z, A);               \
    A = fmaf(h2hi(wz_##K.y), xa.w, A);               \
    A = fmaf(h2lo(wz_##K.z), xb.x, A);               \
    A = fmaf(h2hi(wz_##K.z), xb.y, A);               \
    A = fmaf(h2lo(wz_##K.w), xb.z, A);               \
    A = fmaf(h2hi(wz_##K.w), xb.w, A);               \
  }
    P4(0, z0) P4(1, z1) P4(2, z2) P4(3, z3)
    P4(4, z0) P4(5, z1) P4(6, z2) P4(7, z3)
    P4(8, z0) P4(9, z1) P4(10, z2) P4(11, z3)
    P4(12, z0) P4(13, z1) P4(14, z2) P4(15, z3)
    P4(16, z0) P4(17, z1) P4(18, z2) P4(19, z3)
    P4(20, z0) P4(21, z1) P4(22, z2) P4(23, z3)
    zb[tid] = (z0 + z1) + (z2 + z3);
    __syncthreads();

    // phase 5: LSTM gates, write h
    if (tid < 128) {
      float iv = zb[tid], fv = zb[tid + 128], gv = zb[tid + 256], ov = zb[tid + 384];
      float c = hc[128 + tid];
      float cn = sigm(fv) * c + sigm(iv) * tanh_fast(gv);
      float hn = sigm(ov) * tanh_fast(cn);
      hc[tid] = hn;
      hc[128 + tid] = cn;
      xh[64 + tid] = hn;
      out[((size_t)b * 512 + t) * 128 + tid] = hn;
    }
    __syncthreads();
  }
}

extern "C" void kernel_launch(void* const* d_in, const int* in_sizes, int n_in,
                              void* d_out, int out_size, void* d_ws, size_t ws_size,
                              hipStream_t stream) {
  const float* X   = (const float*)d_in[0];
  const float* Wih = (const float*)d_in[1];
  const float* Whh = (const float*)d_in[2];
  const float* bih = (const float*)d_in[3];
  const float* bhh = (const float*)d_in[4];
  const float* W1  = (const float*)d_in[5];
  const float* b1  = (const float*)d_in[6];
  const float* W2  = (const float*)d_in[7];
  const float* b2  = (const float*)d_in[8];
  const float* W3  = (const float*)d_in[9];
  const float* b3  = (const float*)d_in[10];
  float* out = (float*)d_out;
  float* ws = (float*)d_ws;

  float* s2  = ws;                          // 8,388,608 f32 (32 MB)
  uint4* W1P = (uint4*)(ws + 8388608);      // 16384 uint4 (256 KB)
  uint4* WZP = (uint4*)(ws + 8388608 + 65536);  // 12288 uint4 (192 KB)
  float* bz  = ws + 8388608 + 65536 + 49152;    // 512 f32

  hipLaunchKernelGGL(pack_kernel, dim3(112), dim3(256), 0, stream,
                     W1, Wih, Whh, bih, bhh, W1P, WZP, bz);
  hipLaunchKernelGGL(s2_kernel, dim3(8, 256), dim3(256), 0, stream,
                     X, W2, b2, s2);
  hipLaunchKernelGGL(rnn_kernel, dim3(256), dim3(512), 0, stream,
                     X, s2, W1P, WZP, b1, bz, W3, b3, out);
}